// Round 8
// baseline (24061.417 us; speedup 1.0000x reference)
//
#include <hip/hip_runtime.h>
#include <hip/hip_bf16.h>

// ScannedRNN: 2-cell LayerNorm-GRU scan. T=512, B=128, H=512.
// Reset-bucketed rounds; R8: split each round into cell0/cell1 kernels so
// each kernel's weight read-set (3MB / 2MB) FITS IN the 4MB per-XCD L2.
// (R7 streamed 5MB/WG/group through a 4MB L2 shared by 32 unsynchronized
// WGs -> LRU thrash -> everything served by MALL at ~2.2TB/s.)
// round_a: cell0 GEMM+LN+gates -> h1 (f32) stored INTO ys[t,b] (safe: only
// round_b reads it, then overwrites with h2). round_b: cell1 -> ys/out.
// RCAP=8 rounds (99.6% of cells); d>=8 handled by sequential cleanup.

#define TT 512
#define BB 128
#define HH 512
#define RCAP 8
#define FLAG_WORD 32768

typedef __attribute__((ext_vector_type(8))) short short8;
typedef __attribute__((ext_vector_type(4))) float f32x4;
typedef unsigned int u32;

__device__ __forceinline__ short f2bf(float f) {
  unsigned u = __float_as_uint(f);
  unsigned r = (u + 0x7fffu + ((u >> 16) & 1u)) >> 16;
  return (short)r;
}
__device__ __forceinline__ float bf2f(short s) {
  return __uint_as_float(((unsigned)(unsigned short)s) << 16);
}
__device__ __forceinline__ float sigf(float x) { return 1.f / (1.f + __expf(-x)); }

// tiled weight index: W0 (K=1024): tile=(col>>4)*32+(k>>5); W1 (K=512): (col>>4)*16+(k>>5)
__device__ __forceinline__ size_t w0idx(int col, int k) {
  return (size_t)((col >> 4) * 32 + (k >> 5)) * 512 + (col & 15) * 32 + (k & 31);
}
__device__ __forceinline__ size_t w1idx(int col, int k) {
  return (size_t)((col >> 4) * 16 + (k >> 5)) * 512 + (col & 15) * 32 + (k & 31);
}

// ---------------- pack: weights f32 -> bf16, TILED layout ----------------
__global__ void pack_kernel(const float* __restrict__ Wi, const float* __restrict__ Wh_rz,
                            const float* __restrict__ Wh_n, const void* __restrict__ resets,
                            short* __restrict__ W0p, short* __restrict__ W1p,
                            unsigned* __restrict__ cnt) {
  int gid = blockIdx.x * 256 + threadIdx.x;
  if (gid == 0) {
    const unsigned char* rb = (const unsigned char*)resets;
    unsigned intmode = 1u;
    for (int i = 1; i < 4096; ++i) {
      if ((i & 3) && rb[i]) { intmode = 0u; break; }
    }
    cnt[FLAG_WORD] = intmode;
  }
  const int n0 = 2048 * 128;
  const int n1 = 2048 * 64;
  if (gid < n0) {
    int col = gid & 2047, kb = (gid >> 11) * 8;
    int reg = col >> 9, j = col & 511;
    short8 o;
#pragma unroll
    for (int i = 0; i < 8; ++i) {
      int k = kb + i; float v;
      if (reg == 0)      v = (k < 512) ? Wi[(size_t)k * 1536 + j]        : Wh_rz[(size_t)(k - 512) * 1024 + j];
      else if (reg == 1) v = (k < 512) ? Wi[(size_t)k * 1536 + 512 + j]  : Wh_rz[(size_t)(k - 512) * 1024 + 512 + j];
      else if (reg == 2) v = (k < 512) ? Wi[(size_t)k * 1536 + 1024 + j] : 0.f;
      else               v = (k < 512) ? 0.f                             : Wh_n[(size_t)(k - 512) * 512 + j];
      o[i] = f2bf(v);
    }
    *(short8*)&W0p[w0idx(col, kb)] = o;
  } else if (gid < n0 + n1) {
    int g = gid - n0;
    int col = g & 2047, kb = (g >> 11) * 8;
    int reg = col >> 9, j = col & 511;
    const float* Wi1  = Wi + (size_t)512 * 1536;
    const float* Wrz1 = Wh_rz + (size_t)512 * 1024;
    const float* Wn1  = Wh_n + (size_t)512 * 512;
    short8 o;
#pragma unroll
    for (int i = 0; i < 8; ++i) {
      int k = kb + i; float v;
      if (reg == 0)      v = Wi1[(size_t)k * 1536 + j] + Wrz1[(size_t)k * 1024 + j];
      else if (reg == 1) v = Wi1[(size_t)k * 1536 + 512 + j] + Wrz1[(size_t)k * 1024 + 512 + j];
      else if (reg == 2) v = Wi1[(size_t)k * 1536 + 1024 + j];
      else               v = Wn1[(size_t)k * 512 + j];
      o[i] = f2bf(v);
    }
    *(short8*)&W1p[w1idx(col, kb)] = o;
  }
}

// ---------------- prep: bucket cells by d (single WG) ----------------
__global__ void prep_kernel(const void* __restrict__ resets, unsigned* __restrict__ cnt,
                            u32* __restrict__ bucket) {
  __shared__ u32 hist[RCAP + 1];
  __shared__ u32 cur[RCAP + 1];
  const int tid = threadIdx.x;
  const int rmode = (int)cnt[FLAG_WORD];
  const unsigned char* r8 = (const unsigned char*)resets;
  const int* r32 = (const int*)resets;
  if (tid <= RCAP) hist[tid] = 0;
  __syncthreads();
  if (tid < BB) {
    int d = 0;
    for (int t = 0; t < TT; ++t) {
      bool rs = rmode ? (r32[t * BB + tid] != 0) : (r8[t * BB + tid] != 0);
      d = (t == 0 || rs) ? 0 : d + 1;
      int dd = d < RCAP ? d : RCAP;
      atomicAdd(&hist[dd], 1u);
    }
  }
  __syncthreads();
  if (tid == 0) {
    u32 acc = 0;
    for (int i = 0; i <= RCAP; ++i) { u32 h = hist[i]; cur[i] = acc; cnt[i] = acc; acc += h; }
  }
  __syncthreads();
  if (tid < BB) {
    int d = 0;
    for (int t = 0; t < TT; ++t) {
      bool rs = rmode ? (r32[t * BB + tid] != 0) : (r8[t * BB + tid] != 0);
      d = (t == 0 || rs) ? 0 : d + 1;
      if (d < RCAP) {
        u32 pos = atomicAdd(&cur[d], 1u);
        bucket[pos] = ((u32)t << 7) | (u32)tid;
      }
    }
  }
}

// ---------------- round_a: cell0 for all cells at distance tau -> h1 in ys ----------------
__global__ __launch_bounds__(512, 1) void round_a(
    int tau, const float* __restrict__ ins, const void* __restrict__ resets,
    const float* __restrict__ h0, const float* __restrict__ bi,
    const float* __restrict__ bh_n, const float* __restrict__ ln_s,
    const float* __restrict__ ln_b, const short* __restrict__ W0p,
    const unsigned* __restrict__ cnt, const u32* __restrict__ bucket,
    float* __restrict__ out) {
  __shared__ short lds[81920];          // 160 KB
  short* A0 = lds;                      // [32][1024] bf16, xor-swizzled rows
  short* RB = lds + 32768;              // [32][512] r-gate
  short* ZB = lds + 49152;              // [32][512] z-gate
  short* HB = lds + 65536;              // [32][512] hn
  float* st0 = (float*)lds;             // 256 f32 stats (row0 ins area, dead after GEMM)

  const int tid = threadIdx.x;
  const int l = tid & 63, wv = tid >> 6, c16 = l & 15, kc = l >> 4;
  const int gate = wv >> 1, half = wv & 1;
  const int rmode = (int)cnt[FLAG_WORD];
  const u32 boff = cnt[tau];
  const u32 M = cnt[tau + 1] - boff;
  float* ys = out + BB * HH;
  const int sw0 = (c16 & 7) << 3;
  const int lane16 = c16 * 32 + kc * 8;

  for (u32 g = blockIdx.x; g * 32 < M; g += gridDim.x) {
    const u32 gb = boff + g * 32;
    __syncthreads();

    // ---- stage A0: row = [ins(t,b) | h_in] bf16, swizzled ----
    {
      const int row = tid >> 4, part = tid & 15;
      const u32 m = g * 32 + (u32)row;
      u32 e = (m < M) ? bucket[gb + row] : 0xFFFFFFFFu;
      const int t = (int)((e >> 7) & 511), b = (int)(e & 127);
      const int sw = (row & 7) << 3;
      if (e == 0xFFFFFFFFu) {
        const int k0 = part * 64;
        short8 z = {};
#pragma unroll
        for (int gg = 0; gg < 8; ++gg)
          *(short8*)&A0[row * 1024 + ((k0 + gg * 8) ^ sw)] = z;
      } else if (part < 8) {            // ins half
        const int k0 = part * 64;
        const float* src = ins + (size_t)t * (BB * HH) + (size_t)b * HH + k0;
#pragma unroll
        for (int gg = 0; gg < 8; ++gg) {
          float4 u0 = *(const float4*)(src + gg * 8);
          float4 u1 = *(const float4*)(src + gg * 8 + 4);
          short8 v;
          v[0] = f2bf(u0.x); v[1] = f2bf(u0.y); v[2] = f2bf(u0.z); v[3] = f2bf(u0.w);
          v[4] = f2bf(u1.x); v[5] = f2bf(u1.y); v[6] = f2bf(u1.z); v[7] = f2bf(u1.w);
          *(short8*)&A0[row * 1024 + ((k0 + gg * 8) ^ sw)] = v;
        }
      } else {                          // h half
        const int k0 = (part - 8) * 64;
        const float* src = nullptr;
        bool zero = false;
        if (tau > 0) {
          src = ys + (size_t)(t - 1) * (BB * HH) + (size_t)b * HH + k0;
        } else {
          bool rs = rmode ? (((const int*)resets)[t * BB + b] != 0)
                          : (((const unsigned char*)resets)[t * BB + b] != 0);
          if (rs) zero = true; else src = h0 + (size_t)b * HH + k0;  // t==0 here
        }
#pragma unroll
        for (int gg = 0; gg < 8; ++gg) {
          short8 v = {};
          if (!zero) {
            float4 u0 = *(const float4*)(src + gg * 8);
            float4 u1 = *(const float4*)(src + gg * 8 + 4);
            v[0] = f2bf(u0.x); v[1] = f2bf(u0.y); v[2] = f2bf(u0.z); v[3] = f2bf(u0.w);
            v[4] = f2bf(u1.x); v[5] = f2bf(u1.y); v[6] = f2bf(u1.z); v[7] = f2bf(u1.w);
          }
          *(short8*)&A0[row * 1024 + ((512 + k0 + gg * 8) ^ sw)] = v;
        }
      }
    }
    __syncthreads();

    // ---- cell0 GEMM (B staged 16-wide; zero-tile kb skip) ----
    f32x4 acc[2][16];
#pragma unroll
    for (int rt = 0; rt < 2; ++rt)
#pragma unroll
      for (int ct = 0; ct < 16; ++ct) acc[rt][ct] = (f32x4){0.f, 0.f, 0.f, 0.f};
    {
      const int kb_lo = (gate == 3) ? 16 : 0;
      const int kb_hi = (gate == 2) ? 16 : 32;
#pragma unroll 1
      for (int kb = kb_lo; kb < kb_hi; ++kb) {
        const int k = kb * 32 + kc * 8;
        short8 a0 = *(const short8*)&A0[c16 * 1024 + (k ^ sw0)];
        short8 a1 = *(const short8*)&A0[(16 + c16) * 1024 + (k ^ sw0)];
        short8 bq[16];
#pragma unroll
        for (int ct = 0; ct < 16; ++ct)
          bq[ct] = *(const short8*)(W0p + (size_t)((wv * 16 + ct) * 32 + kb) * 512 + lane16);
#pragma unroll
        for (int ct = 0; ct < 16; ++ct) {
          acc[0][ct] = __builtin_amdgcn_mfma_f32_16x16x32_bf16(a0, bq[ct], acc[0][ct], 0, 0, 0);
          acc[1][ct] = __builtin_amdgcn_mfma_f32_16x16x32_bf16(a1, bq[ct], acc[1][ct], 0, 0, 0);
        }
      }
    }
    __syncthreads();

    // ---- bias + LN stats ----
#pragma unroll
    for (int ct = 0; ct < 16; ++ct) {
      const int col = wv * 256 + ct * 16 + c16;
      const int j = col & 511;
      float bs = (gate == 3) ? bh_n[j] : bi[col];
#pragma unroll
      for (int rt = 0; rt < 2; ++rt)
#pragma unroll
        for (int rr = 0; rr < 4; ++rr) acc[rt][ct][rr] += bs;
    }
    if (gate < 2) {
#pragma unroll
      for (int rt = 0; rt < 2; ++rt)
#pragma unroll
        for (int rr = 0; rr < 4; ++rr) {
          float s = 0.f, q = 0.f;
#pragma unroll
          for (int ct = 0; ct < 16; ++ct) { float v = acc[rt][ct][rr]; s += v; q += v * v; }
#pragma unroll
          for (int o = 8; o >= 1; o >>= 1) { s += __shfl_xor(s, o); q += __shfl_xor(q, o); }
          if (c16 == 0) {
            const int row = rt * 16 + kc * 4 + rr;
            st0[gate * 128 + row * 4 + half * 2 + 0] = s;
            st0[gate * 128 + row * 4 + half * 2 + 1] = q;
          }
        }
    }
    __syncthreads();

    // ---- gates ----
    if (gate < 2) {
#pragma unroll
      for (int rt = 0; rt < 2; ++rt)
#pragma unroll
        for (int rr = 0; rr < 4; ++rr) {
          const int row = rt * 16 + kc * 4 + rr;
          float S = st0[gate * 128 + row * 4 + 0] + st0[gate * 128 + row * 4 + 2];
          float Q = st0[gate * 128 + row * 4 + 1] + st0[gate * 128 + row * 4 + 3];
          float m = S * (1.f / 512.f);
          float vv = Q * (1.f / 512.f) - m * m;
          float ir = rsqrtf(vv + 1e-6f);
#pragma unroll
          for (int ct = 0; ct < 16; ++ct) {
            const int col = wv * 256 + ct * 16 + c16;
            const int j = col & 511;
            float gv = sigf((acc[rt][ct][rr] - m) * ir * ln_s[gate * 512 + j] + ln_b[gate * 512 + j]);
            ((gate == 0) ? RB : ZB)[row * 512 + j] = f2bf(gv);
          }
        }
    } else if (gate == 3) {
#pragma unroll
      for (int rt = 0; rt < 2; ++rt)
#pragma unroll
        for (int rr = 0; rr < 4; ++rr) {
          const int row = rt * 16 + kc * 4 + rr;
#pragma unroll
          for (int ct = 0; ct < 16; ++ct) {
            const int j = (wv * 256 + ct * 16 + c16) & 511;
            HB[row * 512 + j] = f2bf(acc[rt][ct][rr]);
          }
        }
    }
    __syncthreads();

    // ---- combine (gate2 holds xn): h1 -> ys[t,b] (f32) ----
    if (gate == 2) {
#pragma unroll
      for (int rt = 0; rt < 2; ++rt)
#pragma unroll
        for (int rr = 0; rr < 4; ++rr) {
          const int row = rt * 16 + kc * 4 + rr;
          const int sw = (row & 7) << 3;
          const u32 m = g * 32 + (u32)row;
          if (m >= M) continue;
          const u32 e = bucket[gb + row];
          const int t = (int)((e >> 7) & 511), b = (int)(e & 127);
          float* yrow = ys + (size_t)t * (BB * HH) + (size_t)b * HH;
#pragma unroll
          for (int ct = 0; ct < 16; ++ct) {
            const int j = (wv * 256 + ct * 16 + c16) & 511;
            float r = bf2f(RB[row * 512 + j]);
            float z = bf2f(ZB[row * 512 + j]);
            float hn = bf2f(HB[row * 512 + j]);
            float hin = bf2f(A0[row * 1024 + ((512 + j) ^ sw)]);
            float h1 = (1.f - z) * tanhf(acc[rt][ct][rr] + r * hn) + z * hin;
            yrow[j] = h1;
          }
        }
    }
    __syncthreads();
  }
}

// ---------------- round_b: cell1 for bucket tau; reads h1 from ys, writes h2 ----------------
__global__ __launch_bounds__(512, 1) void round_b(
    int tau, const float* __restrict__ bi, const float* __restrict__ bh_n,
    const float* __restrict__ ln_s, const float* __restrict__ ln_b,
    const short* __restrict__ W1p, const unsigned* __restrict__ cnt,
    const u32* __restrict__ bucket, float* __restrict__ out) {
  __shared__ short lds[66560];          // 130 KB
  short* A1 = lds;                      // [32][512] bf16 h1, swizzled
  short* RB = lds + 16384;
  short* ZB = lds + 32768;
  short* HB = lds + 49152;
  float* st1 = (float*)(lds + 65536);   // 256 f32 stats

  const int tid = threadIdx.x;
  const int l = tid & 63, wv = tid >> 6, c16 = l & 15, kc = l >> 4;
  const int gate = wv >> 1, half = wv & 1;
  const u32 boff = cnt[tau];
  const u32 M = cnt[tau + 1] - boff;
  float* ys = out + BB * HH;
  const int sw0 = (c16 & 7) << 3;
  const int lane16 = c16 * 32 + kc * 8;

  for (u32 g = blockIdx.x; g * 32 < M; g += gridDim.x) {
    const u32 gb = boff + g * 32;
    __syncthreads();

    // ---- stage A1: h1 from ys[t,b] (f32 -> bf16, swizzled) ----
    {
      const int row = tid >> 4, part = tid & 15;
      const u32 m = g * 32 + (u32)row;
      u32 e = (m < M) ? bucket[gb + row] : 0xFFFFFFFFu;
      const int t = (int)((e >> 7) & 511), b = (int)(e & 127);
      const int sw = (row & 7) << 3;
      const int k0 = part * 32;
      if (e == 0xFFFFFFFFu) {
        short8 z = {};
#pragma unroll
        for (int gg = 0; gg < 4; ++gg)
          *(short8*)&A1[row * 512 + ((k0 + gg * 8) ^ sw)] = z;
      } else {
        const float* src = ys + (size_t)t * (BB * HH) + (size_t)b * HH + k0;
#pragma unroll
        for (int gg = 0; gg < 4; ++gg) {
          float4 u0 = *(const float4*)(src + gg * 8);
          float4 u1 = *(const float4*)(src + gg * 8 + 4);
          short8 v;
          v[0] = f2bf(u0.x); v[1] = f2bf(u0.y); v[2] = f2bf(u0.z); v[3] = f2bf(u0.w);
          v[4] = f2bf(u1.x); v[5] = f2bf(u1.y); v[6] = f2bf(u1.z); v[7] = f2bf(u1.w);
          *(short8*)&A1[row * 512 + ((k0 + gg * 8) ^ sw)] = v;
        }
      }
    }
    __syncthreads();

    // ---- cell1 GEMM ----
    f32x4 acc[2][16];
#pragma unroll
    for (int rt = 0; rt < 2; ++rt)
#pragma unroll
      for (int ct = 0; ct < 16; ++ct) acc[rt][ct] = (f32x4){0.f, 0.f, 0.f, 0.f};
#pragma unroll 1
    for (int kb = 0; kb < 16; ++kb) {
      const int k = kb * 32 + kc * 8;
      short8 a0 = *(const short8*)&A1[c16 * 512 + (k ^ sw0)];
      short8 a1 = *(const short8*)&A1[(16 + c16) * 512 + (k ^ sw0)];
      short8 bq[16];
#pragma unroll
      for (int ct = 0; ct < 16; ++ct)
        bq[ct] = *(const short8*)(W1p + (size_t)((wv * 16 + ct) * 16 + kb) * 512 + lane16);
#pragma unroll
      for (int ct = 0; ct < 16; ++ct) {
        acc[0][ct] = __builtin_amdgcn_mfma_f32_16x16x32_bf16(a0, bq[ct], acc[0][ct], 0, 0, 0);
        acc[1][ct] = __builtin_amdgcn_mfma_f32_16x16x32_bf16(a1, bq[ct], acc[1][ct], 0, 0, 0);
      }
    }
    __syncthreads();

    // ---- bias + stats ----
#pragma unroll
    for (int ct = 0; ct < 16; ++ct) {
      const int col = wv * 256 + ct * 16 + c16;
      const int j = col & 511;
      float bs = (gate == 3) ? bh_n[512 + j] : bi[1536 + col];
#pragma unroll
      for (int rt = 0; rt < 2; ++rt)
#pragma unroll
        for (int rr = 0; rr < 4; ++rr) acc[rt][ct][rr] += bs;
    }
    if (gate < 2) {
#pragma unroll
      for (int rt = 0; rt < 2; ++rt)
#pragma unroll
        for (int rr = 0; rr < 4; ++rr) {
          float s = 0.f, q = 0.f;
#pragma unroll
          for (int ct = 0; ct < 16; ++ct) { float v = acc[rt][ct][rr]; s += v; q += v * v; }
#pragma unroll
          for (int o = 8; o >= 1; o >>= 1) { s += __shfl_xor(s, o); q += __shfl_xor(q, o); }
          if (c16 == 0) {
            const int row = rt * 16 + kc * 4 + rr;
            st1[gate * 128 + row * 4 + half * 2 + 0] = s;
            st1[gate * 128 + row * 4 + half * 2 + 1] = q;
          }
        }
    }
    __syncthreads();

    // ---- gates ----
    if (gate < 2) {
#pragma unroll
      for (int rt = 0; rt < 2; ++rt)
#pragma unroll
        for (int rr = 0; rr < 4; ++rr) {
          const int row = rt * 16 + kc * 4 + rr;
          float S = st1[gate * 128 + row * 4 + 0] + st1[gate * 128 + row * 4 + 2];
          float Q = st1[gate * 128 + row * 4 + 1] + st1[gate * 128 + row * 4 + 3];
          float m = S * (1.f / 512.f);
          float vv = Q * (1.f / 512.f) - m * m;
          float ir = rsqrtf(vv + 1e-6f);
#pragma unroll
          for (int ct = 0; ct < 16; ++ct) {
            const int col = wv * 256 + ct * 16 + c16;
            const int j = col & 511;
            float gv = sigf((acc[rt][ct][rr] - m) * ir * ln_s[1024 + gate * 512 + j] +
                            ln_b[1024 + gate * 512 + j]);
            ((gate == 0) ? RB : ZB)[row * 512 + j] = f2bf(gv);
          }
        }
    } else if (gate == 3) {
#pragma unroll
      for (int rt = 0; rt < 2; ++rt)
#pragma unroll
        for (int rr = 0; rr < 4; ++rr) {
          const int row = rt * 16 + kc * 4 + rr;
#pragma unroll
          for (int ct = 0; ct < 16; ++ct) {
            const int j = (wv * 256 + ct * 16 + c16) & 511;
            HB[row * 512 + j] = f2bf(acc[rt][ct][rr]);
          }
        }
    }
    __syncthreads();

    // ---- combine -> h2 -> ys[t,b] (+out at t=511) ----
    if (gate == 2) {
#pragma unroll
      for (int rt = 0; rt < 2; ++rt)
#pragma unroll
        for (int rr = 0; rr < 4; ++rr) {
          const int row = rt * 16 + kc * 4 + rr;
          const int sw = (row & 7) << 3;
          const u32 m = g * 32 + (u32)row;
          if (m >= M) continue;
          const u32 e = bucket[gb + row];
          const int t = (int)((e >> 7) & 511), b = (int)(e & 127);
          float* yrow = ys + (size_t)t * (BB * HH) + (size_t)b * HH;
#pragma unroll
          for (int ct = 0; ct < 16; ++ct) {
            const int j = (wv * 256 + ct * 16 + c16) & 511;
            float r = bf2f(RB[row * 512 + j]);
            float z = bf2f(ZB[row * 512 + j]);
            float hn = bf2f(HB[row * 512 + j]);
            float h1v = bf2f(A1[row * 512 + (j ^ sw)]);
            float h2 = (1.f - z) * tanhf(acc[rt][ct][rr] + r * hn) + z * h1v;
            yrow[j] = h2;
            if (t == TT - 1) out[(size_t)b * HH + j] = h2;
          }
        }
    }
    __syncthreads();
  }
}

// ---------------- cleanup: cells with d >= RCAP (expected ~256 cells) ----------------
__global__ __launch_bounds__(256, 1) void cleanup_kernel(
    const float* __restrict__ ins, const void* __restrict__ resets,
    const unsigned* __restrict__ cnt, const float* __restrict__ bi,
    const float* __restrict__ bh_n, const float* __restrict__ ln_s,
    const float* __restrict__ ln_b, const short* __restrict__ W0p,
    const short* __restrict__ W1p, float* __restrict__ out) {
  __shared__ float pre[2048];
  __shared__ float hbuf[512];
  __shared__ float red[4][4];
  const int b = blockIdx.x, tid = threadIdx.x;
  const int wv = tid >> 6, l = tid & 63;
  const int rmode = (int)cnt[FLAG_WORD];
  float* ys = out + BB * HH;
  int d = 0;
  for (int t = 0; t < TT; ++t) {
    bool rs = rmode ? (((const int*)resets)[t * BB + b] != 0)
                    : (((const unsigned char*)resets)[t * BB + b] != 0);
    d = (t == 0 || rs) ? 0 : d + 1;
    if (d < RCAP) continue;
    const float* hin = ys + (size_t)(t - 1) * (BB * HH) + (size_t)b * HH;
    const float* insr = ins + (size_t)t * (BB * HH) + (size_t)b * HH;
    for (int c = tid; c < 2048; c += 256) {
      float s = 0.f;
      for (int k = 0; k < 512; ++k) s += insr[k] * bf2f(W0p[w0idx(c, k)]);
      for (int k = 0; k < 512; ++k) s += hin[k] * bf2f(W0p[w0idx(c, 512 + k)]);
      pre[c] = s;
    }
    __syncthreads();
    float s0 = 0, q0 = 0, s1 = 0, q1 = 0;
    for (int j = tid; j < 512; j += 256) {
      float a = pre[j] + bi[j]; s0 += a; q0 += a * a;
      float c2 = pre[512 + j] + bi[512 + j]; s1 += c2; q1 += c2 * c2;
    }
#pragma unroll
    for (int o = 32; o >= 1; o >>= 1) {
      s0 += __shfl_xor(s0, o); q0 += __shfl_xor(q0, o);
      s1 += __shfl_xor(s1, o); q1 += __shfl_xor(q1, o);
    }
    if (l == 0) { red[wv][0] = s0; red[wv][1] = q0; red[wv][2] = s1; red[wv][3] = q1; }
    __syncthreads();
    float S0 = red[0][0] + red[1][0] + red[2][0] + red[3][0];
    float Q0 = red[0][1] + red[1][1] + red[2][1] + red[3][1];
    float S1 = red[0][2] + red[1][2] + red[2][2] + red[3][2];
    float Q1 = red[0][3] + red[1][3] + red[2][3] + red[3][3];
    float mr = S0 / 512.f, vr = Q0 / 512.f - mr * mr, ir = rsqrtf(vr + 1e-6f);
    float mz = S1 / 512.f, vz = Q1 / 512.f - mz * mz, iz = rsqrtf(vz + 1e-6f);
    __syncthreads();
    for (int j = tid; j < 512; j += 256) {
      float rg = sigf((pre[j] + bi[j] - mr) * ir * ln_s[j] + ln_b[j]);
      float zg = sigf((pre[512 + j] + bi[512 + j] - mz) * iz * ln_s[512 + j] + ln_b[512 + j]);
      float nn = tanhf(pre[1024 + j] + bi[1024 + j] + rg * (pre[1536 + j] + bh_n[j]));
      hbuf[j] = (1.f - zg) * nn + zg * hin[j];
    }
    __syncthreads();
    for (int c = tid; c < 2048; c += 256) {
      float s = 0.f;
      for (int k = 0; k < 512; ++k) s += hbuf[k] * bf2f(W1p[w1idx(c, k)]);
      pre[c] = s;
    }
    __syncthreads();
    s0 = 0; q0 = 0; s1 = 0; q1 = 0;
    for (int j = tid; j < 512; j += 256) {
      float a = pre[j] + bi[1536 + j]; s0 += a; q0 += a * a;
      float c2 = pre[512 + j] + bi[2048 + j]; s1 += c2; q1 += c2 * c2;
    }
#pragma unroll
    for (int o = 32; o >= 1; o >>= 1) {
      s0 += __shfl_xor(s0, o); q0 += __shfl_xor(q0, o);
      s1 += __shfl_xor(s1, o); q1 += __shfl_xor(q1, o);
    }
    if (l == 0) { red[wv][0] = s0; red[wv][1] = q0; red[wv][2] = s1; red[wv][3] = q1; }
    __syncthreads();
    S0 = red[0][0] + red[1][0] + red[2][0] + red[3][0];
    Q0 = red[0][1] + red[1][1] + red[2][1] + red[3][1];
    S1 = red[0][2] + red[1][2] + red[2][2] + red[3][2];
    Q1 = red[0][3] + red[1][3] + red[2][3] + red[3][3];
    mr = S0 / 512.f; vr = Q0 / 512.f - mr * mr; ir = rsqrtf(vr + 1e-6f);
    mz = S1 / 512.f; vz = Q1 / 512.f - mz * mz; iz = rsqrtf(vz + 1e-6f);
    __syncthreads();
    for (int j = tid; j < 512; j += 256) {
      float rg = sigf((pre[j] + bi[1536 + j] - mr) * ir * ln_s[1024 + j] + ln_b[1024 + j]);
      float zg = sigf((pre[512 + j] + bi[2048 + j] - mz) * iz * ln_s[1536 + j] + ln_b[1536 + j]);
      float nn = tanhf(pre[1024 + j] + bi[2560 + j] + rg * (pre[1536 + j] + bh_n[512 + j]));
      float h2 = (1.f - zg) * nn + zg * hbuf[j];
      ys[(size_t)t * (BB * HH) + (size_t)b * HH + j] = h2;
      if (t == TT - 1) out[(size_t)b * HH + j] = h2;
    }
    __syncthreads();
  }
}

extern "C" void kernel_launch(void* const* d_in, const int* in_sizes, int n_in,
                              void* d_out, int out_size, void* d_ws, size_t ws_size,
                              hipStream_t stream) {
  const float* ins   = (const float*)d_in[0];
  const void*  rstp  = d_in[1];
  const float* h0    = (const float*)d_in[2];
  const float* Wi    = (const float*)d_in[3];
  const float* bi    = (const float*)d_in[4];
  const float* Wh_rz = (const float*)d_in[5];
  const float* Wh_n  = (const float*)d_in[6];
  const float* bh_n  = (const float*)d_in[7];
  const float* ln_s  = (const float*)d_in[8];
  const float* ln_b  = (const float*)d_in[9];
  (void)in_sizes; (void)n_in; (void)out_size; (void)ws_size;

  char* ws = (char*)d_ws;
  unsigned* cnt = (unsigned*)ws;                       // off[0..RCAP] + flag @32768
  size_t off = 144 * 1024;
  u32*   bucket = (u32*)(ws + off);  off += (size_t)TT * BB * 4;       // 256 KB
  short* W0p    = (short*)(ws + off); off += (size_t)2048 * 1024 * 2;  // 4 MB
  short* W1p    = (short*)(ws + off); off += (size_t)2048 * 512 * 2;   // 2 MB

  hipMemsetAsync(cnt, 0, (FLAG_WORD + 1) * sizeof(unsigned), stream);
  pack_kernel<<<1536, 256, 0, stream>>>(Wi, Wh_rz, Wh_n, rstp, W0p, W1p, cnt);
  prep_kernel<<<1, 128, 0, stream>>>(rstp, cnt, bucket);
  float* outp = (float*)d_out;
  for (int tau = 0; tau < RCAP; ++tau) {
    round_a<<<256, 512, 0, stream>>>(tau, ins, rstp, h0, bi, bh_n, ln_s, ln_b,
                                     W0p, cnt, bucket, outp);
    round_b<<<256, 512, 0, stream>>>(tau, bi, bh_n, ln_s, ln_b,
                                     W1p, cnt, bucket, outp);
  }
  cleanup_kernel<<<BB, 256, 0, stream>>>(ins, rstp, cnt, bi, bh_n, ln_s, ln_b,
                                         W0p, W1p, outp);
}

// Round 10
// 11679.647 us; speedup vs baseline: 2.0601x; 2.0601x over previous
//
#include <hip/hip_runtime.h>
#include <hip/hip_bf16.h>

// ScannedRNN: 2-cell LayerNorm-GRU scan. T=512, B=128, H=512.
// Reset-bucketed rounds, cell0/cell1 split (weight set 3MB/2MB fits 4MB L2),
// R10 (= R9 fixed): NON-TEMPORAL hints on every streaming access (ins/ys/h0
// reads, h1/h2 writes) so streams stop evicting the L2-resident weights.
// NT builtins require clang ext_vector pointers, not HIP float4 classes.
// RCAP=20: cleanup is an empty scan for random resets.

#define TT 512
#define BB 128
#define HH 512
#define RCAP 20
#define FLAG_WORD 32768

typedef __attribute__((ext_vector_type(8))) short short8;
typedef __attribute__((ext_vector_type(4))) float f32x4;
typedef unsigned int u32;

__device__ __forceinline__ short f2bf(float f) {
  unsigned u = __float_as_uint(f);
  unsigned r = (u + 0x7fffu + ((u >> 16) & 1u)) >> 16;
  return (short)r;
}
__device__ __forceinline__ float bf2f(short s) {
  return __uint_as_float(((unsigned)(unsigned short)s) << 16);
}
__device__ __forceinline__ float sigf(float x) { return 1.f / (1.f + __expf(-x)); }
// non-temporal streaming access (evict-first: keeps weights L2-resident)
__device__ __forceinline__ f32x4 ldnt4(const float* p) {
  return __builtin_nontemporal_load((const f32x4*)p);
}
__device__ __forceinline__ void stnt(float* p, float v) {
  __builtin_nontemporal_store(v, p);
}

// tiled weight index: W0 (K=1024): tile=(col>>4)*32+(k>>5); W1 (K=512): (col>>4)*16+(k>>5)
__device__ __forceinline__ size_t w0idx(int col, int k) {
  return (size_t)((col >> 4) * 32 + (k >> 5)) * 512 + (col & 15) * 32 + (k & 31);
}
__device__ __forceinline__ size_t w1idx(int col, int k) {
  return (size_t)((col >> 4) * 16 + (k >> 5)) * 512 + (col & 15) * 32 + (k & 31);
}

// ---------------- pack: weights f32 -> bf16, TILED layout ----------------
__global__ void pack_kernel(const float* __restrict__ Wi, const float* __restrict__ Wh_rz,
                            const float* __restrict__ Wh_n, const void* __restrict__ resets,
                            short* __restrict__ W0p, short* __restrict__ W1p,
                            unsigned* __restrict__ cnt) {
  int gid = blockIdx.x * 256 + threadIdx.x;
  if (gid == 0) {
    const unsigned char* rb = (const unsigned char*)resets;
    unsigned intmode = 1u;
    for (int i = 1; i < 4096; ++i) {
      if ((i & 3) && rb[i]) { intmode = 0u; break; }
    }
    cnt[FLAG_WORD] = intmode;
  }
  const int n0 = 2048 * 128;
  const int n1 = 2048 * 64;
  if (gid < n0) {
    int col = gid & 2047, kb = (gid >> 11) * 8;
    int reg = col >> 9, j = col & 511;
    short8 o;
#pragma unroll
    for (int i = 0; i < 8; ++i) {
      int k = kb + i; float v;
      if (reg == 0)      v = (k < 512) ? Wi[(size_t)k * 1536 + j]        : Wh_rz[(size_t)(k - 512) * 1024 + j];
      else if (reg == 1) v = (k < 512) ? Wi[(size_t)k * 1536 + 512 + j]  : Wh_rz[(size_t)(k - 512) * 1024 + 512 + j];
      else if (reg == 2) v = (k < 512) ? Wi[(size_t)k * 1536 + 1024 + j] : 0.f;
      else               v = (k < 512) ? 0.f                             : Wh_n[(size_t)(k - 512) * 512 + j];
      o[i] = f2bf(v);
    }
    *(short8*)&W0p[w0idx(col, kb)] = o;
  } else if (gid < n0 + n1) {
    int g = gid - n0;
    int col = g & 2047, kb = (g >> 11) * 8;
    int reg = col >> 9, j = col & 511;
    const float* Wi1  = Wi + (size_t)512 * 1536;
    const float* Wrz1 = Wh_rz + (size_t)512 * 1024;
    const float* Wn1  = Wh_n + (size_t)512 * 512;
    short8 o;
#pragma unroll
    for (int i = 0; i < 8; ++i) {
      int k = kb + i; float v;
      if (reg == 0)      v = Wi1[(size_t)k * 1536 + j] + Wrz1[(size_t)k * 1024 + j];
      else if (reg == 1) v = Wi1[(size_t)k * 1536 + 512 + j] + Wrz1[(size_t)k * 1024 + 512 + j];
      else if (reg == 2) v = Wi1[(size_t)k * 1536 + 1024 + j];
      else               v = Wn1[(size_t)k * 512 + j];
      o[i] = f2bf(v);
    }
    *(short8*)&W1p[w1idx(col, kb)] = o;
  }
}

// ---------------- prep: bucket cells by d (single WG) ----------------
__global__ void prep_kernel(const void* __restrict__ resets, unsigned* __restrict__ cnt,
                            u32* __restrict__ bucket) {
  __shared__ u32 hist[RCAP + 1];
  __shared__ u32 cur[RCAP + 1];
  const int tid = threadIdx.x;
  const int rmode = (int)cnt[FLAG_WORD];
  const unsigned char* r8 = (const unsigned char*)resets;
  const int* r32 = (const int*)resets;
  if (tid <= RCAP) hist[tid] = 0;
  __syncthreads();
  if (tid < BB) {
    int d = 0;
    for (int t = 0; t < TT; ++t) {
      bool rs = rmode ? (r32[t * BB + tid] != 0) : (r8[t * BB + tid] != 0);
      d = (t == 0 || rs) ? 0 : d + 1;
      int dd = d < RCAP ? d : RCAP;
      atomicAdd(&hist[dd], 1u);
    }
  }
  __syncthreads();
  if (tid == 0) {
    u32 acc = 0;
    for (int i = 0; i <= RCAP; ++i) { u32 h = hist[i]; cur[i] = acc; cnt[i] = acc; acc += h; }
  }
  __syncthreads();
  if (tid < BB) {
    int d = 0;
    for (int t = 0; t < TT; ++t) {
      bool rs = rmode ? (r32[t * BB + tid] != 0) : (r8[t * BB + tid] != 0);
      d = (t == 0 || rs) ? 0 : d + 1;
      if (d < RCAP) {
        u32 pos = atomicAdd(&cur[d], 1u);
        bucket[pos] = ((u32)t << 7) | (u32)tid;
      }
    }
  }
}

// ---------------- round_a: cell0 for bucket tau -> h1 (f32) into ys[t,b] ----------------
__global__ __launch_bounds__(512, 1) void round_a(
    int tau, const float* __restrict__ ins, const void* __restrict__ resets,
    const float* __restrict__ h0, const float* __restrict__ bi,
    const float* __restrict__ bh_n, const float* __restrict__ ln_s,
    const float* __restrict__ ln_b, const short* __restrict__ W0p,
    const unsigned* __restrict__ cnt, const u32* __restrict__ bucket,
    float* __restrict__ out) {
  __shared__ short lds[81920];          // 160 KB
  short* A0 = lds;                      // [32][1024] bf16, xor-swizzled rows
  short* RB = lds + 32768;              // [32][512] r-gate
  short* ZB = lds + 49152;              // [32][512] z-gate
  short* HB = lds + 65536;              // [32][512] hn
  float* st0 = (float*)lds;             // 256 f32 stats (row0 ins area, dead after GEMM)

  const int tid = threadIdx.x;
  const int l = tid & 63, wv = tid >> 6, c16 = l & 15, kc = l >> 4;
  const int gate = wv >> 1, half = wv & 1;
  const int rmode = (int)cnt[FLAG_WORD];
  const u32 boff = cnt[tau];
  const u32 M = cnt[tau + 1] - boff;
  float* ys = out + BB * HH;
  const int sw0 = (c16 & 7) << 3;
  const int lane16 = c16 * 32 + kc * 8;

  for (u32 g = blockIdx.x; g * 32 < M; g += gridDim.x) {
    const u32 gb = boff + g * 32;
    __syncthreads();

    // ---- stage A0: row = [ins(t,b) | h_in] bf16, swizzled; NT loads ----
    {
      const int row = tid >> 4, part = tid & 15;
      const u32 m = g * 32 + (u32)row;
      u32 e = (m < M) ? bucket[gb + row] : 0xFFFFFFFFu;
      const int t = (int)((e >> 7) & 511), b = (int)(e & 127);
      const int sw = (row & 7) << 3;
      if (e == 0xFFFFFFFFu) {
        const int k0 = part * 64;
        short8 z = {};
#pragma unroll
        for (int gg = 0; gg < 8; ++gg)
          *(short8*)&A0[row * 1024 + ((k0 + gg * 8) ^ sw)] = z;
      } else if (part < 8) {            // ins half
        const int k0 = part * 64;
        const float* src = ins + (size_t)t * (BB * HH) + (size_t)b * HH + k0;
#pragma unroll
        for (int gg = 0; gg < 8; ++gg) {
          f32x4 u0 = ldnt4(src + gg * 8);
          f32x4 u1 = ldnt4(src + gg * 8 + 4);
          short8 v;
          v[0] = f2bf(u0.x); v[1] = f2bf(u0.y); v[2] = f2bf(u0.z); v[3] = f2bf(u0.w);
          v[4] = f2bf(u1.x); v[5] = f2bf(u1.y); v[6] = f2bf(u1.z); v[7] = f2bf(u1.w);
          *(short8*)&A0[row * 1024 + ((k0 + gg * 8) ^ sw)] = v;
        }
      } else {                          // h half
        const int k0 = (part - 8) * 64;
        const float* src = nullptr;
        bool zero = false;
        if (tau > 0) {
          src = ys + (size_t)(t - 1) * (BB * HH) + (size_t)b * HH + k0;
        } else {
          bool rs = rmode ? (((const int*)resets)[t * BB + b] != 0)
                          : (((const unsigned char*)resets)[t * BB + b] != 0);
          if (rs) zero = true; else src = h0 + (size_t)b * HH + k0;  // t==0 here
        }
#pragma unroll
        for (int gg = 0; gg < 8; ++gg) {
          short8 v = {};
          if (!zero) {
            f32x4 u0 = ldnt4(src + gg * 8);
            f32x4 u1 = ldnt4(src + gg * 8 + 4);
            v[0] = f2bf(u0.x); v[1] = f2bf(u0.y); v[2] = f2bf(u0.z); v[3] = f2bf(u0.w);
            v[4] = f2bf(u1.x); v[5] = f2bf(u1.y); v[6] = f2bf(u1.z); v[7] = f2bf(u1.w);
          }
          *(short8*)&A0[row * 1024 + ((512 + k0 + gg * 8) ^ sw)] = v;
        }
      }
    }
    __syncthreads();

    // ---- cell0 GEMM (B staged 16-wide; zero-tile kb skip; W cached) ----
    f32x4 acc[2][16];
#pragma unroll
    for (int rt = 0; rt < 2; ++rt)
#pragma unroll
      for (int ct = 0; ct < 16; ++ct) acc[rt][ct] = (f32x4){0.f, 0.f, 0.f, 0.f};
    {
      const int kb_lo = (gate == 3) ? 16 : 0;
      const int kb_hi = (gate == 2) ? 16 : 32;
#pragma unroll 1
      for (int kb = kb_lo; kb < kb_hi; ++kb) {
        const int k = kb * 32 + kc * 8;
        short8 a0 = *(const short8*)&A0[c16 * 1024 + (k ^ sw0)];
        short8 a1 = *(const short8*)&A0[(16 + c16) * 1024 + (k ^ sw0)];
        short8 bq[16];
#pragma unroll
        for (int ct = 0; ct < 16; ++ct)
          bq[ct] = *(const short8*)(W0p + (size_t)((wv * 16 + ct) * 32 + kb) * 512 + lane16);
#pragma unroll
        for (int ct = 0; ct < 16; ++ct) {
          acc[0][ct] = __builtin_amdgcn_mfma_f32_16x16x32_bf16(a0, bq[ct], acc[0][ct], 0, 0, 0);
          acc[1][ct] = __builtin_amdgcn_mfma_f32_16x16x32_bf16(a1, bq[ct], acc[1][ct], 0, 0, 0);
        }
      }
    }
    __syncthreads();

    // ---- bias + LN stats ----
#pragma unroll
    for (int ct = 0; ct < 16; ++ct) {
      const int col = wv * 256 + ct * 16 + c16;
      const int j = col & 511;
      float bs = (gate == 3) ? bh_n[j] : bi[col];
#pragma unroll
      for (int rt = 0; rt < 2; ++rt)
#pragma unroll
        for (int rr = 0; rr < 4; ++rr) acc[rt][ct][rr] += bs;
    }
    if (gate < 2) {
#pragma unroll
      for (int rt = 0; rt < 2; ++rt)
#pragma unroll
        for (int rr = 0; rr < 4; ++rr) {
          float s = 0.f, q = 0.f;
#pragma unroll
          for (int ct = 0; ct < 16; ++ct) { float v = acc[rt][ct][rr]; s += v; q += v * v; }
#pragma unroll
          for (int o = 8; o >= 1; o >>= 1) { s += __shfl_xor(s, o); q += __shfl_xor(q, o); }
          if (c16 == 0) {
            const int row = rt * 16 + kc * 4 + rr;
            st0[gate * 128 + row * 4 + half * 2 + 0] = s;
            st0[gate * 128 + row * 4 + half * 2 + 1] = q;
          }
        }
    }
    __syncthreads();

    // ---- gates ----
    if (gate < 2) {
#pragma unroll
      for (int rt = 0; rt < 2; ++rt)
#pragma unroll
        for (int rr = 0; rr < 4; ++rr) {
          const int row = rt * 16 + kc * 4 + rr;
          float S = st0[gate * 128 + row * 4 + 0] + st0[gate * 128 + row * 4 + 2];
          float Q = st0[gate * 128 + row * 4 + 1] + st0[gate * 128 + row * 4 + 3];
          float m = S * (1.f / 512.f);
          float vv = Q * (1.f / 512.f) - m * m;
          float ir = rsqrtf(vv + 1e-6f);
#pragma unroll
          for (int ct = 0; ct < 16; ++ct) {
            const int col = wv * 256 + ct * 16 + c16;
            const int j = col & 511;
            float gv = sigf((acc[rt][ct][rr] - m) * ir * ln_s[gate * 512 + j] + ln_b[gate * 512 + j]);
            ((gate == 0) ? RB : ZB)[row * 512 + j] = f2bf(gv);
          }
        }
    } else if (gate == 3) {
#pragma unroll
      for (int rt = 0; rt < 2; ++rt)
#pragma unroll
        for (int rr = 0; rr < 4; ++rr) {
          const int row = rt * 16 + kc * 4 + rr;
#pragma unroll
          for (int ct = 0; ct < 16; ++ct) {
            const int j = (wv * 256 + ct * 16 + c16) & 511;
            HB[row * 512 + j] = f2bf(acc[rt][ct][rr]);
          }
        }
    }
    __syncthreads();

    // ---- combine (gate2 holds xn): h1 -> ys[t,b] (f32, NT store) ----
    if (gate == 2) {
#pragma unroll
      for (int rt = 0; rt < 2; ++rt)
#pragma unroll
        for (int rr = 0; rr < 4; ++rr) {
          const int row = rt * 16 + kc * 4 + rr;
          const int sw = (row & 7) << 3;
          const u32 m = g * 32 + (u32)row;
          if (m >= M) continue;
          const u32 e = bucket[gb + row];
          const int t = (int)((e >> 7) & 511), b = (int)(e & 127);
          float* yrow = ys + (size_t)t * (BB * HH) + (size_t)b * HH;
#pragma unroll
          for (int ct = 0; ct < 16; ++ct) {
            const int j = (wv * 256 + ct * 16 + c16) & 511;
            float r = bf2f(RB[row * 512 + j]);
            float z = bf2f(ZB[row * 512 + j]);
            float hn = bf2f(HB[row * 512 + j]);
            float hin = bf2f(A0[row * 1024 + ((512 + j) ^ sw)]);
            float h1 = (1.f - z) * tanhf(acc[rt][ct][rr] + r * hn) + z * hin;
            stnt(&yrow[j], h1);
          }
        }
    }
    __syncthreads();
  }
}

// ---------------- round_b: cell1 for bucket tau; h1 from ys -> h2 ----------------
__global__ __launch_bounds__(512, 1) void round_b(
    int tau, const float* __restrict__ bi, const float* __restrict__ bh_n,
    const float* __restrict__ ln_s, const float* __restrict__ ln_b,
    const short* __restrict__ W1p, const unsigned* __restrict__ cnt,
    const u32* __restrict__ bucket, float* __restrict__ out) {
  __shared__ short lds[66560];          // 130 KB
  short* A1 = lds;                      // [32][512] bf16 h1, swizzled
  short* RB = lds + 16384;
  short* ZB = lds + 32768;
  short* HB = lds + 49152;
  float* st1 = (float*)(lds + 65536);   // 256 f32 stats

  const int tid = threadIdx.x;
  const int l = tid & 63, wv = tid >> 6, c16 = l & 15, kc = l >> 4;
  const int gate = wv >> 1, half = wv & 1;
  const u32 boff = cnt[tau];
  const u32 M = cnt[tau + 1] - boff;
  float* ys = out + BB * HH;
  const int sw0 = (c16 & 7) << 3;
  const int lane16 = c16 * 32 + kc * 8;

  for (u32 g = blockIdx.x; g * 32 < M; g += gridDim.x) {
    const u32 gb = boff + g * 32;
    __syncthreads();

    // ---- stage A1: h1 from ys[t,b] (NT load, f32 -> bf16, swizzled) ----
    {
      const int row = tid >> 4, part = tid & 15;
      const u32 m = g * 32 + (u32)row;
      u32 e = (m < M) ? bucket[gb + row] : 0xFFFFFFFFu;
      const int t = (int)((e >> 7) & 511), b = (int)(e & 127);
      const int sw = (row & 7) << 3;
      const int k0 = part * 32;
      if (e == 0xFFFFFFFFu) {
        short8 z = {};
#pragma unroll
        for (int gg = 0; gg < 4; ++gg)
          *(short8*)&A1[row * 512 + ((k0 + gg * 8) ^ sw)] = z;
      } else {
        const float* src = ys + (size_t)t * (BB * HH) + (size_t)b * HH + k0;
#pragma unroll
        for (int gg = 0; gg < 4; ++gg) {
          f32x4 u0 = ldnt4(src + gg * 8);
          f32x4 u1 = ldnt4(src + gg * 8 + 4);
          short8 v;
          v[0] = f2bf(u0.x); v[1] = f2bf(u0.y); v[2] = f2bf(u0.z); v[3] = f2bf(u0.w);
          v[4] = f2bf(u1.x); v[5] = f2bf(u1.y); v[6] = f2bf(u1.z); v[7] = f2bf(u1.w);
          *(short8*)&A1[row * 512 + ((k0 + gg * 8) ^ sw)] = v;
        }
      }
    }
    __syncthreads();

    // ---- cell1 GEMM ----
    f32x4 acc[2][16];
#pragma unroll
    for (int rt = 0; rt < 2; ++rt)
#pragma unroll
      for (int ct = 0; ct < 16; ++ct) acc[rt][ct] = (f32x4){0.f, 0.f, 0.f, 0.f};
#pragma unroll 1
    for (int kb = 0; kb < 16; ++kb) {
      const int k = kb * 32 + kc * 8;
      short8 a0 = *(const short8*)&A1[c16 * 512 + (k ^ sw0)];
      short8 a1 = *(const short8*)&A1[(16 + c16) * 512 + (k ^ sw0)];
      short8 bq[16];
#pragma unroll
      for (int ct = 0; ct < 16; ++ct)
        bq[ct] = *(const short8*)(W1p + (size_t)((wv * 16 + ct) * 16 + kb) * 512 + lane16);
#pragma unroll
      for (int ct = 0; ct < 16; ++ct) {
        acc[0][ct] = __builtin_amdgcn_mfma_f32_16x16x32_bf16(a0, bq[ct], acc[0][ct], 0, 0, 0);
        acc[1][ct] = __builtin_amdgcn_mfma_f32_16x16x32_bf16(a1, bq[ct], acc[1][ct], 0, 0, 0);
      }
    }
    __syncthreads();

    // ---- bias + stats ----
#pragma unroll
    for (int ct = 0; ct < 16; ++ct) {
      const int col = wv * 256 + ct * 16 + c16;
      const int j = col & 511;
      float bs = (gate == 3) ? bh_n[512 + j] : bi[1536 + col];
#pragma unroll
      for (int rt = 0; rt < 2; ++rt)
#pragma unroll
        for (int rr = 0; rr < 4; ++rr) acc[rt][ct][rr] += bs;
    }
    if (gate < 2) {
#pragma unroll
      for (int rt = 0; rt < 2; ++rt)
#pragma unroll
        for (int rr = 0; rr < 4; ++rr) {
          float s = 0.f, q = 0.f;
#pragma unroll
          for (int ct = 0; ct < 16; ++ct) { float v = acc[rt][ct][rr]; s += v; q += v * v; }
#pragma unroll
          for (int o = 8; o >= 1; o >>= 1) { s += __shfl_xor(s, o); q += __shfl_xor(q, o); }
          if (c16 == 0) {
            const int row = rt * 16 + kc * 4 + rr;
            st1[gate * 128 + row * 4 + half * 2 + 0] = s;
            st1[gate * 128 + row * 4 + half * 2 + 1] = q;
          }
        }
    }
    __syncthreads();

    // ---- gates ----
    if (gate < 2) {
#pragma unroll
      for (int rt = 0; rt < 2; ++rt)
#pragma unroll
        for (int rr = 0; rr < 4; ++rr) {
          const int row = rt * 16 + kc * 4 + rr;
          float S = st1[gate * 128 + row * 4 + 0] + st1[gate * 128 + row * 4 + 2];
          float Q = st1[gate * 128 + row * 4 + 1] + st1[gate * 128 + row * 4 + 3];
          float m = S * (1.f / 512.f);
          float vv = Q * (1.f / 512.f) - m * m;
          float ir = rsqrtf(vv + 1e-6f);
#pragma unroll
          for (int ct = 0; ct < 16; ++ct) {
            const int col = wv * 256 + ct * 16 + c16;
            const int j = col & 511;
            float gv = sigf((acc[rt][ct][rr] - m) * ir * ln_s[1024 + gate * 512 + j] +
                            ln_b[1024 + gate * 512 + j]);
            ((gate == 0) ? RB : ZB)[row * 512 + j] = f2bf(gv);
          }
        }
    } else if (gate == 3) {
#pragma unroll
      for (int rt = 0; rt < 2; ++rt)
#pragma unroll
        for (int rr = 0; rr < 4; ++rr) {
          const int row = rt * 16 + kc * 4 + rr;
#pragma unroll
          for (int ct = 0; ct < 16; ++ct) {
            const int j = (wv * 256 + ct * 16 + c16) & 511;
            HB[row * 512 + j] = f2bf(acc[rt][ct][rr]);
          }
        }
    }
    __syncthreads();

    // ---- combine -> h2 -> ys[t,b] (+out at t=511), NT stores ----
    if (gate == 2) {
#pragma unroll
      for (int rt = 0; rt < 2; ++rt)
#pragma unroll
        for (int rr = 0; rr < 4; ++rr) {
          const int row = rt * 16 + kc * 4 + rr;
          const int sw = (row & 7) << 3;
          const u32 m = g * 32 + (u32)row;
          if (m >= M) continue;
          const u32 e = bucket[gb + row];
          const int t = (int)((e >> 7) & 511), b = (int)(e & 127);
          float* yrow = ys + (size_t)t * (BB * HH) + (size_t)b * HH;
#pragma unroll
          for (int ct = 0; ct < 16; ++ct) {
            const int j = (wv * 256 + ct * 16 + c16) & 511;
            float r = bf2f(RB[row * 512 + j]);
            float z = bf2f(ZB[row * 512 + j]);
            float hn = bf2f(HB[row * 512 + j]);
            float h1v = bf2f(A1[row * 512 + (j ^ sw)]);
            float h2 = (1.f - z) * tanhf(acc[rt][ct][rr] + r * hn) + z * h1v;
            stnt(&yrow[j], h2);
            if (t == TT - 1) stnt(&out[(size_t)b * HH + j], h2);
          }
        }
    }
    __syncthreads();
  }
}

// ---------------- cleanup: cells with d >= RCAP (expected none) ----------------
__global__ __launch_bounds__(256, 1) void cleanup_kernel(
    const float* __restrict__ ins, const void* __restrict__ resets,
    const unsigned* __restrict__ cnt, const float* __restrict__ bi,
    const float* __restrict__ bh_n, const float* __restrict__ ln_s,
    const float* __restrict__ ln_b, const short* __restrict__ W0p,
    const short* __restrict__ W1p, float* __restrict__ out) {
  __shared__ float pre[2048];
  __shared__ float hbuf[512];
  __shared__ float red[4][4];
  const int b = blockIdx.x, tid = threadIdx.x;
  const int wv = tid >> 6, l = tid & 63;
  const int rmode = (int)cnt[FLAG_WORD];
  float* ys = out + BB * HH;
  int d = 0;
  for (int t = 0; t < TT; ++t) {
    bool rs = rmode ? (((const int*)resets)[t * BB + b] != 0)
                    : (((const unsigned char*)resets)[t * BB + b] != 0);
    d = (t == 0 || rs) ? 0 : d + 1;
    if (d < RCAP) continue;
    const float* hin = ys + (size_t)(t - 1) * (BB * HH) + (size_t)b * HH;
    const float* insr = ins + (size_t)t * (BB * HH) + (size_t)b * HH;
    for (int c = tid; c < 2048; c += 256) {
      float s = 0.f;
      for (int k = 0; k < 512; ++k) s += insr[k] * bf2f(W0p[w0idx(c, k)]);
      for (int k = 0; k < 512; ++k) s += hin[k] * bf2f(W0p[w0idx(c, 512 + k)]);
      pre[c] = s;
    }
    __syncthreads();
    float s0 = 0, q0 = 0, s1 = 0, q1 = 0;
    for (int j = tid; j < 512; j += 256) {
      float a = pre[j] + bi[j]; s0 += a; q0 += a * a;
      float c2 = pre[512 + j] + bi[512 + j]; s1 += c2; q1 += c2 * c2;
    }
#pragma unroll
    for (int o = 32; o >= 1; o >>= 1) {
      s0 += __shfl_xor(s0, o); q0 += __shfl_xor(q0, o);
      s1 += __shfl_xor(s1, o); q1 += __shfl_xor(q1, o);
    }
    if (l == 0) { red[wv][0] = s0; red[wv][1] = q0; red[wv][2] = s1; red[wv][3] = q1; }
    __syncthreads();
    float S0 = red[0][0] + red[1][0] + red[2][0] + red[3][0];
    float Q0 = red[0][1] + red[1][1] + red[2][1] + red[3][1];
    float S1 = red[0][2] + red[1][2] + red[2][2] + red[3][2];
    float Q1 = red[0][3] + red[1][3] + red[2][3] + red[3][3];
    float mr = S0 / 512.f, vr = Q0 / 512.f - mr * mr, ir = rsqrtf(vr + 1e-6f);
    float mz = S1 / 512.f, vz = Q1 / 512.f - mz * mz, iz = rsqrtf(vz + 1e-6f);
    __syncthreads();
    for (int j = tid; j < 512; j += 256) {
      float rg = sigf((pre[j] + bi[j] - mr) * ir * ln_s[j] + ln_b[j]);
      float zg = sigf((pre[512 + j] + bi[512 + j] - mz) * iz * ln_s[512 + j] + ln_b[512 + j]);
      float nn = tanhf(pre[1024 + j] + bi[1024 + j] + rg * (pre[1536 + j] + bh_n[j]));
      hbuf[j] = (1.f - zg) * nn + zg * hin[j];
    }
    __syncthreads();
    for (int c = tid; c < 2048; c += 256) {
      float s = 0.f;
      for (int k = 0; k < 512; ++k) s += hbuf[k] * bf2f(W1p[w1idx(c, k)]);
      pre[c] = s;
    }
    __syncthreads();
    s0 = 0; q0 = 0; s1 = 0; q1 = 0;
    for (int j = tid; j < 512; j += 256) {
      float a = pre[j] + bi[1536 + j]; s0 += a; q0 += a * a;
      float c2 = pre[512 + j] + bi[2048 + j]; s1 += c2; q1 += c2 * c2;
    }
#pragma unroll
    for (int o = 32; o >= 1; o >>= 1) {
      s0 += __shfl_xor(s0, o); q0 += __shfl_xor(q0, o);
      s1 += __shfl_xor(s1, o); q1 += __shfl_xor(q1, o);
    }
    if (l == 0) { red[wv][0] = s0; red[wv][1] = q0; red[wv][2] = s1; red[wv][3] = q1; }
    __syncthreads();
    S0 = red[0][0] + red[1][0] + red[2][0] + red[3][0];
    Q0 = red[0][1] + red[1][1] + red[2][1] + red[3][1];
    S1 = red[0][2] + red[1][2] + red[2][2] + red[3][2];
    Q1 = red[0][3] + red[1][3] + red[2][3] + red[3][3];
    mr = S0 / 512.f; vr = Q0 / 512.f - mr * mr; ir = rsqrtf(vr + 1e-6f);
    mz = S1 / 512.f; vz = Q1 / 512.f - mz * mz; iz = rsqrtf(vz + 1e-6f);
    __syncthreads();
    for (int j = tid; j < 512; j += 256) {
      float rg = sigf((pre[j] + bi[1536 + j] - mr) * ir * ln_s[1024 + j] + ln_b[1024 + j]);
      float zg = sigf((pre[512 + j] + bi[2048 + j] - mz) * iz * ln_s[1536 + j] + ln_b[1536 + j]);
      float nn = tanhf(pre[1024 + j] + bi[2560 + j] + rg * (pre[1536 + j] + bh_n[512 + j]));
      float h2 = (1.f - zg) * nn + zg * hbuf[j];
      ys[(size_t)t * (BB * HH) + (size_t)b * HH + j] = h2;
      if (t == TT - 1) out[(size_t)b * HH + j] = h2;
    }
    __syncthreads();
  }
}

extern "C" void kernel_launch(void* const* d_in, const int* in_sizes, int n_in,
                              void* d_out, int out_size, void* d_ws, size_t ws_size,
                              hipStream_t stream) {
  const float* ins   = (const float*)d_in[0];
  const void*  rstp  = d_in[1];
  const float* h0    = (const float*)d_in[2];
  const float* Wi    = (const float*)d_in[3];
  const float* bi    = (const float*)d_in[4];
  const float* Wh_rz = (const float*)d_in[5];
  const float* Wh_n  = (const float*)d_in[6];
  const float* bh_n  = (const float*)d_in[7];
  const float* ln_s  = (const float*)d_in[8];
  const float* ln_b  = (const float*)d_in[9];
  (void)in_sizes; (void)n_in; (void)out_size; (void)ws_size;

  char* ws = (char*)d_ws;
  unsigned* cnt = (unsigned*)ws;                       // off[0..RCAP] + flag @32768
  size_t off = 144 * 1024;
  u32*   bucket = (u32*)(ws + off);  off += (size_t)TT * BB * 4;       // 256 KB
  short* W0p    = (short*)(ws + off); off += (size_t)2048 * 1024 * 2;  // 4 MB
  short* W1p    = (short*)(ws + off); off += (size_t)2048 * 512 * 2;   // 2 MB

  (void)hipMemsetAsync(cnt, 0, (FLAG_WORD + 1) * sizeof(unsigned), stream);
  pack_kernel<<<1536, 256, 0, stream>>>(Wi, Wh_rz, Wh_n, rstp, W0p, W1p, cnt);
  prep_kernel<<<1, 128, 0, stream>>>(rstp, cnt, bucket);
  float* outp = (float*)d_out;
  for (int tau = 0; tau < RCAP; ++tau) {
    round_a<<<256, 512, 0, stream>>>(tau, ins, rstp, h0, bi, bh_n, ln_s, ln_b,
                                     W0p, cnt, bucket, outp);
    round_b<<<256, 512, 0, stream>>>(tau, bi, bh_n, ln_s, ln_b,
                                     W1p, cnt, bucket, outp);
  }
  cleanup_kernel<<<BB, 256, 0, stream>>>(ins, rstp, cnt, bi, bh_n, ln_s, ln_b,
                                         W0p, W1p, outp);
}